// Round 17
// baseline (797.611 us; speedup 1.0000x reference)
//
#include <hip/hip_runtime.h>
#include <math.h>

// GraphStructureLearning: B=16, P=4096, DM=N=64, NLAYER=3, HID=4096, NH=16, dh=256, L=4.
// Round 17: MLP GEMM is LDS-BANDWIDTH-bound (128KB LDS traffic per CU-step vs 466cy
// MFMA -> 2.5-3x). Fix: NO-LDS register-direct GEMM — operands are fragment-ordered
// in global memory, so each wave global_load_dwordx4's its fragments straight to
// VGPRs (L1 broadcasts the wc/wr-duplicate reads). Zero LDS, zero barriers.
// Everything else identical to round 15 (best, 557.9us).

#define B16 16
#define PDIM 4096
#define NNODE 64
#define NCHUNK 32
#define KCG 128

typedef __attribute__((ext_vector_type(8))) short bf16x8;
typedef __attribute__((ext_vector_type(4))) float f32x4;
typedef __attribute__((ext_vector_type(4))) unsigned short us4;
typedef __attribute__((ext_vector_type(8))) unsigned short us8;

// f32 -> (hi bf16, lo bf16), RNE both; x ~ hi + lo with |err| <= 2^-18 |x|.
__device__ inline void split2(float x, unsigned short& h, unsigned short& l) {
  unsigned u = __float_as_uint(x);
  unsigned hu = (u + 0x7fffu + ((u >> 16) & 1u)) & 0xffff0000u;
  h = (unsigned short)(hu >> 16);
  float lo = x - __uint_as_float(hu);
  unsigned u2 = __float_as_uint(lo);
  l = (unsigned short)((u2 + 0x7fffu + ((u2 >> 16) & 1u)) >> 16);
}

__device__ inline void gload16(const void* g, void* lds) {
  __builtin_amdgcn_global_load_lds((const unsigned int*)g, (unsigned int*)lds, 16, 0, 0);
}

// ---------------- transpose x[B][4096][64] -> tiled split A (and f32 h for fallback) --
__global__ __launch_bounds__(256) void k_transpose(const float* __restrict__ x,
                                                   float* __restrict__ h,
                                                   unsigned short* __restrict__ AhT,
                                                   unsigned short* __restrict__ AlT,
                                                   int mode) {
  __shared__ float t[64][65];
  int b = blockIdx.y;
  int p0 = blockIdx.x * 64;
  const float* xb = x + (size_t)b * PDIM * NNODE;
#pragma unroll
  for (int i = 0; i < 16; ++i) {
    int e = i * 256 + threadIdx.x;
    int p = e >> 6, n = e & 63;
    t[p][n] = xb[(size_t)p0 * 64 + e];
  }
  __syncthreads();
  if (mode != 2) {
    float* hb = h + (size_t)b * NNODE * PDIM;
#pragma unroll
    for (int i = 0; i < 16; ++i) {
      int e = i * 256 + threadIdx.x;
      int n = e >> 6, p = e & 63;
      hb[(size_t)n * PDIM + p0 + p] = t[p][n];
    }
  }
  if (mode == 0) return;
#pragma unroll
  for (int j = 0; j < 2; ++j) {
    int cid = j * 256 + threadIdx.x;    // 512 cells: 64 n x 8 k-groups
    int n2 = cid >> 3, kg8 = cid & 7;
    us8 hv_, lv_;
#pragma unroll
    for (int e = 0; e < 8; ++e) {
      unsigned short hh, ll;
      split2(t[kg8 * 8 + e][n2], hh, ll);
      hv_[e] = hh; lv_[e] = ll;
    }
    int m = b * 64 + n2;
    int ks = (p0 >> 5) + (kg8 >> 2);
    size_t idx = (((size_t)(m >> 7) * 128 + ks) * 8 + ((m >> 4) & 7)) * 512 +
                 (size_t)((n2 & 15) + 16 * (kg8 & 3)) * 8;
    *(us8*)&AhT[idx] = hv_;
    *(us8*)&AlT[idx] = lv_;
  }
}

// ---------------- weight split+tile (MLP only): W[4096][4096] f32 -> WhT/WlT --------
__global__ __launch_bounds__(256) void k_wsplit(const float* __restrict__ W,
                                                unsigned short* __restrict__ WhT,
                                                unsigned short* __restrict__ WlT) {
  __shared__ float Wt[32][132];
  int nb = blockIdx.x, kb = blockIdx.y;
  int tid = threadIdx.x;
#pragma unroll
  for (int i = 0; i < 4; ++i) {
    int idx = i * 256 + tid;
    int row = idx >> 5, c4 = idx & 31;
    float4 v = *(const float4*)&W[(size_t)(kb * 32 + row) * 4096 + nb * 128 + c4 * 4];
    *(float4*)&Wt[row][c4 * 4] = v;
  }
  __syncthreads();
#pragma unroll
  for (int j = 0; j < 2; ++j) {
    int cid = j * 256 + tid;            // 512 cells: 128 n x 4 k-groups
    int nl = cid & 127, kg = cid >> 7;
    us8 hv_, lv_;
#pragma unroll
    for (int e = 0; e < 8; ++e) {
      unsigned short hh, ll;
      split2(Wt[kg * 8 + e][nl], hh, ll);
      hv_[e] = hh; lv_[e] = ll;
    }
    size_t idx = (((size_t)nb * 128 + kb) * 8 + (nl >> 4)) * 512 +
                 (size_t)((nl & 15) + 16 * kg) * 8;
    *(us8*)&WhT[idx] = hv_;
    *(us8*)&WlT[idx] = lv_;
  }
}

// ---------------- MLP bf16 GEMM: NO-LDS register-direct fragments ----------------
// BM=128 BN=128 BK=32, grid (nb=32, mb=8, z=2); 512 thr = 8 waves (2wr x 4wc);
// wave tile 64x32 (4mt x 2nt). Fragments loaded straight from the tiled global
// layout: frag addr = (rowgrp*Ksteps + ks)*4096 + tile*512 + l*8. No LDS, no barriers.
__global__ __launch_bounds__(512) void k_gemm_bf16(
    const unsigned short* __restrict__ Ah, const unsigned short* __restrict__ Al,
    const unsigned short* __restrict__ Bh, const unsigned short* __restrict__ Bl,
    float* __restrict__ Cp, int Ksteps, int ksplit, int N, int mstore) {
  int tid = threadIdx.x;
  int l = tid & 63, wid = tid >> 6;
  int wr = wid >> 2, wc = wid & 3;
  int nb = blockIdx.x, mb = blockIdx.y, z = blockIdx.z;
  int spp = Ksteps / ksplit;
  int ks0 = z * spp;

  // fragment base addresses (advance 4096 shorts per k-step)
  size_t abase = ((size_t)mb * Ksteps + ks0) * 4096 + (size_t)(wr * 4) * 512 + l * 8;
  size_t bbase = ((size_t)nb * Ksteps + ks0) * 4096 + (size_t)(wc * 2) * 512 + l * 8;

  f32x4 acc[4][2];
#pragma unroll
  for (int i = 0; i < 4; ++i)
#pragma unroll
    for (int j = 0; j < 2; ++j) acc[i][j] = (f32x4){0.f, 0.f, 0.f, 0.f};

  for (int t = 0; t < spp; ++t) {
    size_t ao = abase + (size_t)t * 4096;
    size_t bo = bbase + (size_t)t * 4096;
    bf16x8 ah[4], al4[4], bh2[2], bl2[2];
#pragma unroll
    for (int mt = 0; mt < 4; ++mt) {
      ah[mt]  = *(const bf16x8*)(Ah + ao + mt * 512);
      al4[mt] = *(const bf16x8*)(Al + ao + mt * 512);
    }
#pragma unroll
    for (int nt = 0; nt < 2; ++nt) {
      bh2[nt] = *(const bf16x8*)(Bh + bo + nt * 512);
      bl2[nt] = *(const bf16x8*)(Bl + bo + nt * 512);
    }
#pragma unroll
    for (int mt = 0; mt < 4; ++mt)
#pragma unroll
      for (int nt = 0; nt < 2; ++nt) {
        acc[mt][nt] = __builtin_amdgcn_mfma_f32_16x16x32_bf16(ah[mt],  bh2[nt], acc[mt][nt], 0, 0, 0);
        acc[mt][nt] = __builtin_amdgcn_mfma_f32_16x16x32_bf16(ah[mt],  bl2[nt], acc[mt][nt], 0, 0, 0);
        acc[mt][nt] = __builtin_amdgcn_mfma_f32_16x16x32_bf16(al4[mt], bh2[nt], acc[mt][nt], 0, 0, 0);
      }
  }

  int n0 = nb * 128, m0 = mb * 128;
  float* Cz = Cp + (size_t)z * mstore * N;
#pragma unroll
  for (int mt = 0; mt < 4; ++mt)
#pragma unroll
    for (int nt = 0; nt < 2; ++nt) {
      int col = n0 + wc * 32 + nt * 16 + (l & 15);
#pragma unroll
      for (int r = 0; r < 4; ++r) {
        int row = m0 + wr * 64 + mt * 16 + ((l >> 4) << 2) + r;
        if (row < mstore) Cz[(size_t)row * N + col] = acc[mt][nt][r];
      }
    }
}

// ---------------- QKV/O GEMM: A pre-tiled (rows 0..63), W split on-the-fly ----------
__global__ __launch_bounds__(512) void k_gemm_wsf32(
    const unsigned short* __restrict__ Ah, const unsigned short* __restrict__ Al,
    const float* __restrict__ W0, const float* __restrict__ W1,
    const float* __restrict__ W2, float* __restrict__ Cp, int ksplit) {
  __shared__ unsigned short sAh[2][2048], sAl[2][2048];   // 16 KB
  __shared__ unsigned short sBh[2][4096], sBl[2][4096];   // 32 KB
  int tid = threadIdx.x;
  int l = tid & 63, wid = tid >> 6;
  int wr = wid >> 2, wc = wid & 3;
  int nb = blockIdx.x, z = blockIdx.z;
  int mat = z / ksplit, kz = z - mat * ksplit;
  const float* W = (mat == 0) ? W0 : ((mat == 1) ? W1 : W2);
  int nsteps = 128 / ksplit;
  int ks0 = kz * nsteps;
  int n0 = nb * 128;

  const float* wbase = W + (size_t)((l >> 4) * 8) * 4096 + n0 + wid * 16 + (l & 15);
  int sidx = wid * 512 + l * 8;

  f32x4 acc[2][2];
#pragma unroll
  for (int i = 0; i < 2; ++i)
#pragma unroll
    for (int j = 0; j < 2; ++j) acc[i][j] = (f32x4){0.f, 0.f, 0.f, 0.f};

  {
    if (tid < 256) gload16(Ah + (size_t)ks0 * 4096 + tid * 8, &sAh[0][tid * 8]);
    else           gload16(Al + (size_t)ks0 * 4096 + (tid - 256) * 8, &sAl[0][(tid - 256) * 8]);
    float wv[8];
#pragma unroll
    for (int e = 0; e < 8; ++e) wv[e] = wbase[(size_t)ks0 * 131072 + (size_t)e * 4096];
    us8 hi, lo;
#pragma unroll
    for (int e = 0; e < 8; ++e) {
      unsigned short hh, ll;
      split2(wv[e], hh, ll);
      hi[e] = hh; lo[e] = ll;
    }
    *(us8*)&sBh[0][sidx] = hi;
    *(us8*)&sBl[0][sidx] = lo;
  }
  __syncthreads();

  int buf = 0;
  for (int t = 0; t < nsteps; ++t) {
    bool more = (t + 1 < nsteps);
    float wv[8];
    if (more) {
      int ks = ks0 + t + 1;
      if (tid < 256) gload16(Ah + (size_t)ks * 4096 + tid * 8, &sAh[buf ^ 1][tid * 8]);
      else           gload16(Al + (size_t)ks * 4096 + (tid - 256) * 8, &sAl[buf ^ 1][(tid - 256) * 8]);
#pragma unroll
      for (int e = 0; e < 8; ++e) wv[e] = wbase[(size_t)ks * 131072 + (size_t)e * 4096];
    }
    bf16x8 aH[2], aL[2], bH[2], bL[2];
#pragma unroll
    for (int i = 0; i < 2; ++i) {
      aH[i] = *(const bf16x8*)&sAh[buf][(wr * 2 + i) * 512 + l * 8];
      aL[i] = *(const bf16x8*)&sAl[buf][(wr * 2 + i) * 512 + l * 8];
      bH[i] = *(const bf16x8*)&sBh[buf][(wc * 2 + i) * 512 + l * 8];
      bL[i] = *(const bf16x8*)&sBl[buf][(wc * 2 + i) * 512 + l * 8];
    }
#pragma unroll
    for (int i = 0; i < 2; ++i)
#pragma unroll
      for (int j = 0; j < 2; ++j) {
        acc[i][j] = __builtin_amdgcn_mfma_f32_16x16x32_bf16(aH[i], bH[j], acc[i][j], 0, 0, 0);
        acc[i][j] = __builtin_amdgcn_mfma_f32_16x16x32_bf16(aH[i], bL[j], acc[i][j], 0, 0, 0);
        acc[i][j] = __builtin_amdgcn_mfma_f32_16x16x32_bf16(aL[i], bH[j], acc[i][j], 0, 0, 0);
      }
    if (more) {
      us8 hi, lo;
#pragma unroll
      for (int e = 0; e < 8; ++e) {
        unsigned short hh, ll;
        split2(wv[e], hh, ll);
        hi[e] = hh; lo[e] = ll;
      }
      *(us8*)&sBh[buf ^ 1][sidx] = hi;
      *(us8*)&sBl[buf ^ 1][sidx] = lo;
    }
    __syncthreads();
    buf ^= 1;
  }

  float* Cz = Cp + (size_t)z * 262144;
#pragma unroll
  for (int i = 0; i < 2; ++i)
#pragma unroll
    for (int j = 0; j < 2; ++j) {
      int col = n0 + wc * 32 + j * 16 + (l & 15);
#pragma unroll
      for (int r = 0; r < 4; ++r) {
        int row = (wr * 2 + i) * 16 + ((l >> 4) << 2) + r;
        Cz[(size_t)row * 4096 + col] = acc[i][j][r];
      }
    }
}

// ---------------- fused gram: reduce(Cp)+bias -> split -> tile -> MFMA ----------------
// grid (zk=32, b=16) -> 512 blocks (2/CU). 4 steps of k-chunk 32.
__global__ __launch_bounds__(256) void k_gram_fuse(
    const float* __restrict__ Cp, const float* __restrict__ bias,
    float* __restrict__ Gp, float* __restrict__ Sp, int nparts) {
  __shared__ unsigned short sZh[2048], sZl[2048];
  int zk = blockIdx.x, b = blockIdx.y;
  int tid = threadIdx.x;
  int l = tid & 63, w = tid >> 6;
  int srow = tid >> 2, skq = tid & 3;
  const float* cbase = Cp + (size_t)(b * 64 + srow) * 4096;
  int swidx = (srow >> 4) * 512 + (skq * 16 + (srow & 15)) * 8;

  f32x4 acc[4], racc;
#pragma unroll
  for (int j = 0; j < 4; ++j) acc[j] = (f32x4){0.f, 0.f, 0.f, 0.f};
  racc = (f32x4){0.f, 0.f, 0.f, 0.f};
  bf16x8 ones;
#pragma unroll
  for (int e = 0; e < 8; ++e) ones[e] = (short)0x3F80;    // bf16 1.0

  for (int s = 0; s < 4; ++s) {
    int k0 = zk * 128 + s * 32 + skq * 8;
    float v[8];
#pragma unroll
    for (int e = 0; e < 8; ++e) v[e] = bias[k0 + e];
    for (int p = 0; p < nparts; ++p) {
      const float* pp = cbase + (size_t)p * 4194304 + k0;
      float4 a0 = *(const float4*)pp;
      float4 a1 = *(const float4*)(pp + 4);
      v[0] += a0.x; v[1] += a0.y; v[2] += a0.z; v[3] += a0.w;
      v[4] += a1.x; v[5] += a1.y; v[6] += a1.z; v[7] += a1.w;
    }
    us8 hi, lo;
#pragma unroll
    for (int e = 0; e < 8; ++e) {
      unsigned short hh, ll;
      split2(v[e], hh, ll);
      hi[e] = hh; lo[e] = ll;
    }
    *(us8*)&sZh[swidx] = hi;
    *(us8*)&sZl[swidx] = lo;
    __syncthreads();
    bf16x8 bh[4], bl4[4];
#pragma unroll
    for (int nt = 0; nt < 4; ++nt) {
      bh[nt]  = *(const bf16x8*)&sZh[nt * 512 + l * 8];
      bl4[nt] = *(const bf16x8*)&sZl[nt * 512 + l * 8];
    }
    bf16x8 ah = bh[w], al = bl4[w];
#pragma unroll
    for (int nt = 0; nt < 4; ++nt) {
      acc[nt] = __builtin_amdgcn_mfma_f32_16x16x32_bf16(ah, bh[nt], acc[nt], 0, 0, 0);
      acc[nt] = __builtin_amdgcn_mfma_f32_16x16x32_bf16(ah, bl4[nt], acc[nt], 0, 0, 0);
      acc[nt] = __builtin_amdgcn_mfma_f32_16x16x32_bf16(al, bh[nt], acc[nt], 0, 0, 0);
    }
    racc = __builtin_amdgcn_mfma_f32_16x16x32_bf16(ah, ones, racc, 0, 0, 0);
    racc = __builtin_amdgcn_mfma_f32_16x16x32_bf16(al, ones, racc, 0, 0, 0);
    __syncthreads();
  }

  float* Gz = Gp + ((size_t)zk * B16 + b) * 4096;
#pragma unroll
  for (int nt = 0; nt < 4; ++nt) {
    int col = nt * 16 + (l & 15);
#pragma unroll
    for (int r = 0; r < 4; ++r) {
      int row = w * 16 + ((l >> 4) << 2) + r;
      Gz[row * 64 + col] = acc[nt][r];
    }
  }
  if ((l & 15) == 0) {
    float* Sz = Sp + ((size_t)zk * B16 + b) * 64;
#pragma unroll
    for (int r = 0; r < 4; ++r) Sz[w * 16 + ((l >> 4) << 2) + r] = racc[r];
  }
}

// ---------------- gram via MFMA on pre-split tiles (slot 0) ----------------
__global__ __launch_bounds__(256) void k_gram_mfma(
    const unsigned short* __restrict__ Zh, const unsigned short* __restrict__ Zl,
    float* __restrict__ Gp, float* __restrict__ Sp,
    int bs1, int ks_stride, int nsteps) {
  __shared__ unsigned short sZh[2][2048], sZl[2][2048];
  int z = blockIdx.x, b = blockIdx.y;
  int tid = threadIdx.x;
  int l = tid & 63, w = tid >> 6;
  size_t zbase = (size_t)(b >> 1) * 524288 + (size_t)(b & 1) * bs1;
  int ks0 = z * nsteps;

  f32x4 acc[4], racc;
#pragma unroll
  for (int j = 0; j < 4; ++j) acc[j] = (f32x4){0.f, 0.f, 0.f, 0.f};
  racc = (f32x4){0.f, 0.f, 0.f, 0.f};
  bf16x8 ones;
#pragma unroll
  for (int e = 0; e < 8; ++e) ones[e] = (short)0x3F80;

  gload16(Zh + zbase + (size_t)ks0 * ks_stride + tid * 8, &sZh[0][tid * 8]);
  gload16(Zl + zbase + (size_t)ks0 * ks_stride + tid * 8, &sZl[0][tid * 8]);
  __syncthreads();

  int buf = 0;
  for (int t = 0; t < nsteps; ++t) {
    if (t + 1 < nsteps) {
      size_t off = zbase + (size_t)(ks0 + t + 1) * ks_stride + tid * 8;
      gload16(Zh + off, &sZh[buf ^ 1][tid * 8]);
      gload16(Zl + off, &sZl[buf ^ 1][tid * 8]);
    }
    bf16x8 bh[4], bl4[4];
#pragma unroll
    for (int nt = 0; nt < 4; ++nt) {
      bh[nt]  = *(const bf16x8*)&sZh[buf][nt * 512 + l * 8];
      bl4[nt] = *(const bf16x8*)&sZl[buf][nt * 512 + l * 8];
    }
    bf16x8 ah = bh[w], al = bl4[w];
#pragma unroll
    for (int nt = 0; nt < 4; ++nt) {
      acc[nt] = __builtin_amdgcn_mfma_f32_16x16x32_bf16(ah, bh[nt], acc[nt], 0, 0, 0);
      acc[nt] = __builtin_amdgcn_mfma_f32_16x16x32_bf16(ah, bl4[nt], acc[nt], 0, 0, 0);
      acc[nt] = __builtin_amdgcn_mfma_f32_16x16x32_bf16(al, bh[nt], acc[nt], 0, 0, 0);
    }
    racc = __builtin_amdgcn_mfma_f32_16x16x32_bf16(ah, ones, racc, 0, 0, 0);
    racc = __builtin_amdgcn_mfma_f32_16x16x32_bf16(al, ones, racc, 0, 0, 0);
    __syncthreads();
    buf ^= 1;
  }

  float* Gz = Gp + ((size_t)z * B16 + b) * 4096;
#pragma unroll
  for (int nt = 0; nt < 4; ++nt) {
    int col = nt * 16 + (l & 15);
#pragma unroll
    for (int r = 0; r < 4; ++r) {
      int row = w * 16 + ((l >> 4) << 2) + r;
      Gz[row * 64 + col] = acc[nt][r];
    }
  }
  if ((l & 15) == 0) {
    float* Sz = Sp + ((size_t)z * B16 + b) * 64;
#pragma unroll
    for (int r = 0; r < 4; ++r) Sz[w * 16 + ((l >> 4) << 2) + r] = racc[r];
  }
}

// ---------------- gram partial reduce (nc chunks) ----------------
__global__ __launch_bounds__(256) void k_gred(const float* __restrict__ Gp,
                                              const float* __restrict__ Sp,
                                              float* __restrict__ G,
                                              float* __restrict__ S, int slot, int nc) {
  int idx = blockIdx.x * 256 + threadIdx.x;
  if (idx < 65536) {
    float s = 0.f;
    for (int c = 0; c < nc; ++c) s += Gp[(size_t)c * 65536 + idx];
    G[(size_t)slot * 65536 + idx] = s;
  } else if (idx < 66560) {
    int i2 = idx - 65536;
    float s = 0.f;
    for (int c = 0; c < nc; ++c) s += Sp[(size_t)c * 1024 + i2];
    S[(size_t)slot * 1024 + i2] = s;
  }
}

// ---------------- QKV reduce (16 partials each), one launch ----------------
__global__ __launch_bounds__(256) void k_redqkv(const float* __restrict__ Cp,
                                                const float* __restrict__ bq,
                                                const float* __restrict__ bk,
                                                const float* __restrict__ bv,
                                                float* __restrict__ q,
                                                float* __restrict__ k,
                                                float* __restrict__ v) {
  int idx = blockIdx.x * 256 + threadIdx.x;   // 3 * 262144
  int mat = idx >> 18;
  int rn = idx & ((1 << 18) - 1);
  int n = rn & 4095;
  const float* base = Cp + (size_t)mat * 16 * 262144;
  float s = 0.f;
#pragma unroll
  for (int p = 0; p < 16; ++p) s += base[(size_t)p * 262144 + rn];
  if (mat == 0) q[rn] = s + bq[n];
  else if (mat == 1) k[rn] = s + bk[n];
  else v[rn] = s + bv[n];
}

// ---------------- generic partial reduce + bias (+threshold) ----------------
__global__ __launch_bounds__(256) void k_redN(const float* __restrict__ Cp,
                                              const float* __restrict__ bias,
                                              float* __restrict__ dst,
                                              int nparts, int thr) {
  int idx = blockIdx.x * 256 + threadIdx.x;   // 262,144
  float s = bias[idx & 4095];
  for (int p = 0; p < nparts; ++p) s += Cp[(size_t)p * 262144 + idx];
  if (thr) s = (s > 0.5f) ? s : 0.f;
  dst[idx] = s;
}

__device__ inline float wmax64(float v) {
#pragma unroll
  for (int off = 32; off; off >>= 1) v = fmaxf(v, __shfl_xor(v, off));
  return v;
}

// ---------------- adjacency: rank-based top-8, 256 threads ----------------
__global__ __launch_bounds__(256) void k_adj_t(const float* __restrict__ G,
                                               const float* __restrict__ S,
                                               unsigned short* __restrict__ tokh,
                                               unsigned short* __restrict__ tokl) {
  __shared__ float Fm[64][64];
  __shared__ float nrm[64], mm[64];
  int b = blockIdx.x >> 2, lz = blockIdx.x & 3;
  int tid = threadIdx.x;
  int j = tid & 63, w = tid >> 6;
  const float* Gb = G + ((size_t)lz * B16 + b) * 4096;
  const float* Sb = S + ((size_t)lz * B16 + b) * 64;
  if (tid < 64) {
    float nj = sqrtf(Gb[tid * 64 + tid]);
    nrm[tid] = nj;
    mm[tid] = Sb[tid] / nj;
  }
  __syncthreads();
  for (int i = w; i < 64; i += 4) {
    float g = Gb[i * 64 + j];
    float sim = g / (nrm[i] * nrm[j]);
    Fm[i][j] = mm[i] * mm[j] * sim * sim;
  }
  __syncthreads();
  for (int i = w; i < 64; i += 4) {
    float f = Fm[i][j];
    int cnt = 0;
#pragma unroll
    for (int u4 = 0; u4 < 16; ++u4) {
      float4 q = *(const float4*)&Fm[i][u4 * 4];
      cnt += (q.x > f) + (q.y > f) + (q.z > f) + (q.w > f);
    }
    float cand = (cnt <= 7) ? f : INFINITY;
#pragma unroll
    for (int off = 32; off; off >>= 1) cand = fminf(cand, __shfl_xor(cand, off));
    float fm = (f >= cand) ? fmaxf(f, 0.f) : 0.f;
    Fm[i][j] = fm;
  }
  __syncthreads();
  int r = b * 4 + lz;
  int mt = r >> 4, rl = r & 15;
#pragma unroll
  for (int c = 0; c < 2; ++c) {
    int cid = tid * 2 + c;
    int jj0 = cid >> 3, g = cid & 7;
    us8 hv_, lv_;
#pragma unroll
    for (int e = 0; e < 8; ++e) {
      int kcol = g * 8 + e;
      float val = 0.5f * (Fm[jj0][kcol] + Fm[kcol][jj0]);
      unsigned short hh, ll;
      split2(val, hh, ll);
      hv_[e] = hh; lv_[e] = ll;
    }
    int ks = jj0 * 2 + (g >> 2);
    size_t idx = ((size_t)ks * 8 + mt) * 512 + (size_t)(rl + 16 * (g & 3)) * 8;
    *(us8*)&tokh[idx] = hv_;
    *(us8*)&tokl[idx] = lv_;
  }
}

// ---------------- attention, tiled split ctx output ----------------
__global__ __launch_bounds__(64) void k_attn_t(const float* __restrict__ q,
                                               const float* __restrict__ k,
                                               const float* __restrict__ v,
                                               unsigned short* __restrict__ ctxh,
                                               unsigned short* __restrict__ ctxl) {
  __shared__ float cb[4][256];
  int hd = blockIdx.x, b = blockIdx.y;
  int t = threadIdx.x;
  float qr[4][4], kr[4][4], vr[4][4];
#pragma unroll
  for (int l = 0; l < 4; ++l)
#pragma unroll
    for (int s = 0; s < 4; ++s) {
      size_t off = ((size_t)(b * 4 + l)) * 4096 + hd * 256 + t + s * 64;
      qr[l][s] = q[off]; kr[l][s] = k[off]; vr[l][s] = v[off];
    }
  float sc[4][4];
#pragma unroll
  for (int l = 0; l < 4; ++l)
#pragma unroll
    for (int m = 0; m < 4; ++m) {
      float p = 0.f;
#pragma unroll
      for (int s = 0; s < 4; ++s) p = fmaf(qr[l][s], kr[m][s], p);
#pragma unroll
      for (int off = 32; off; off >>= 1) p += __shfl_xor(p, off);
      sc[l][m] = p * (1.0f / 16.0f);
    }
  float at[4][4];
#pragma unroll
  for (int l = 0; l < 4; ++l) {
    float mx = fmaxf(fmaxf(sc[l][0], sc[l][1]), fmaxf(sc[l][2], sc[l][3]));
    float e0 = expf(sc[l][0] - mx), e1 = expf(sc[l][1] - mx);
    float e2 = expf(sc[l][2] - mx), e3 = expf(sc[l][3] - mx);
    float d = e0 + e1 + e2 + e3;
    at[l][0] = e0 / d; at[l][1] = e1 / d; at[l][2] = e2 / d; at[l][3] = e3 / d;
  }
#pragma unroll
  for (int l = 0; l < 4; ++l)
#pragma unroll
    for (int s = 0; s < 4; ++s) {
      float c = 0.f;
#pragma unroll
      for (int m = 0; m < 4; ++m) c = fmaf(at[l][m], vr[m][s], c);
      cb[l][s * 64 + t] = c;
    }
  __syncthreads();
  int lq = t >> 4, c16 = t & 15;
  int mt = b >> 2, rl = (b & 3) * 4 + lq;
#pragma unroll
  for (int e8 = 0; e8 < 2; ++e8) {
    us8 hv_, lv_;
#pragma unroll
    for (int e = 0; e < 8; ++e) {
      unsigned short hh, ll;
      split2(cb[lq][c16 * 16 + e8 * 8 + e], hh, ll);
      hv_[e] = hh; lv_[e] = ll;
    }
    int ks = hd * 8 + (c16 >> 1);
    size_t idx = ((size_t)ks * 8 + mt) * 512 + (size_t)(rl + 16 * ((c16 * 2 + e8) & 3)) * 8;
    *(us8*)&ctxh[idx] = hv_;
    *(us8*)&ctxl[idx] = lv_;
  }
}

// ================= FALLBACK (round-3 proven path) =================
__global__ __launch_bounds__(256) void k_gram_partial(const float* __restrict__ Z,
                                                      float* __restrict__ Gp,
                                                      float* __restrict__ Sp) {
  __shared__ float Zt[KCG][68];
  int c = blockIdx.x, b = blockIdx.y;
  int tid = threadIdx.x;
  const float* Zb = Z + (size_t)b * NNODE * PDIM + c * KCG;
#pragma unroll
  for (int i = 0; i < 32; ++i) {
    int e = i * 256 + tid;
    int r = e >> 7, kk = e & 127;
    Zt[kk][r] = Zb[(size_t)r * PDIM + kk];
  }
  __syncthreads();
  int ii = tid >> 2, j0 = (tid & 3) << 4;
  float acc[16] = {};
  for (int kk = 0; kk < KCG; ++kk) {
    float zi = Zt[kk][ii];
    float4 z0 = *(const float4*)&Zt[kk][j0 + 0];
    float4 z1 = *(const float4*)&Zt[kk][j0 + 4];
    float4 z2 = *(const float4*)&Zt[kk][j0 + 8];
    float4 z3 = *(const float4*)&Zt[kk][j0 + 12];
    acc[0] = fmaf(zi, z0.x, acc[0]);   acc[1] = fmaf(zi, z0.y, acc[1]);
    acc[2] = fmaf(zi, z0.z, acc[2]);   acc[3] = fmaf(zi, z0.w, acc[3]);
    acc[4] = fmaf(zi, z1.x, acc[4]);   acc[5] = fmaf(zi, z1.y, acc[5]);
    acc[6] = fmaf(zi, z1.z, acc[6]);   acc[7] = fmaf(zi, z1.w, acc[7]);
    acc[8] = fmaf(zi, z2.x, acc[8]);   acc[9] = fmaf(zi, z2.y, acc[9]);
    acc[10] = fmaf(zi, z2.z, acc[10]); acc[11] = fmaf(zi, z2.w, acc[11]);
    acc[12] = fmaf(zi, z3.x, acc[12]); acc[13] = fmaf(zi, z3.y, acc[13]);
    acc[14] = fmaf(zi, z3.z, acc[14]); acc[15] = fmaf(zi, z3.w, acc[15]);
  }
  float* gp = Gp + ((size_t)c * B16 + b) * 4096 + ii * 64 + j0;
#pragma unroll
  for (int j = 0; j < 16; ++j) gp[j] = acc[j];
  if (tid < 64) {
    float s = 0.f;
    for (int kk = 0; kk < KCG; ++kk) s += Zt[kk][tid];
    Sp[((size_t)c * B16 + b) * 64 + tid] = s;
  }
}

__global__ __launch_bounds__(256) void k_gram_reduce(const float* __restrict__ Gp,
                                                     const float* __restrict__ Sp,
                                                     float* __restrict__ G,
                                                     float* __restrict__ S, int slot) {
  int idx = blockIdx.x * 256 + threadIdx.x;
  if (idx < B16 * 4096) {
    float s = 0.f;
    for (int c = 0; c < NCHUNK; ++c) s += Gp[(size_t)c * (B16 * 4096) + idx];
    G[(size_t)slot * (B16 * 4096) + idx] = s;
  } else {
    int idx2 = idx - B16 * 4096;
    float s = 0.f;
    for (int c = 0; c < NCHUNK; ++c) s += Sp[(size_t)c * (B16 * 64) + idx2];
    S[(size_t)slot * (B16 * 64) + idx2] = s;
  }
}

__global__ __launch_bounds__(256) void k_gemm_mfma(
    const float* __restrict__ A, const float* __restrict__ B0,
    const float* __restrict__ B1, const float* __restrict__ B2,
    const float* __restrict__ bias, float* __restrict__ C,
    int mrows, int mstore, int N, int K, int ksplit) {
  __shared__ __align__(16) unsigned short sA[2][8][64][8];
  __shared__ __align__(16) unsigned short sB[2][8][64][8];
  int z = blockIdx.z;
  int mat = z / ksplit, ks = z - mat * ksplit;
  const float* Bm = (mat == 0) ? B0 : ((mat == 1) ? B1 : B2);
  int kchunk = K / ksplit;
  int k0 = ks * kchunk, k1 = k0 + kchunk;
  int tid = threadIdx.x;
  int l = tid & 63;
  int wr = (tid >> 7) & 1, wc = (tid >> 6) & 1;
  int m0 = blockIdx.y * 128, n0g = blockIdx.x * 128;
  bool activeM = (m0 + wr * 64) < mstore;
  int am = tid >> 1;
  int arow = m0 + am; if (arow >= mrows) arow = mrows - 1;
  const float* Arow = A + (size_t)arow * K;
  int amt = am >> 4;
  int bk = tid >> 3;
  int bnb = (tid & 7) * 4;
  int bg = bk >> 3, bslot = bk & 7;
  f32x4 acc[4][4];
#pragma unroll
  for (int i = 0; i < 4; ++i)
#pragma unroll
    for (int j = 0; j < 4; ++j) acc[i][j] = (f32x4){0.f, 0.f, 0.f, 0.f};
  for (int kb = k0; kb < k1; kb += 32) {
    __syncthreads();
#pragma unroll
    for (int i = 0; i < 4; ++i) {
      int kq = (tid & 1) * 4 + i * 8;
      float4 a = *(const float4*)(Arow + kb + kq);
      unsigned short h0, h1, h2, h3, l0, l1, l2, l3;
      split2(a.x, h0, l0); split2(a.y, h1, l1);
      split2(a.z, h2, l2); split2(a.w, h3, l3);
      int lane_t = (am & 15) + 16 * (kq >> 3);
      int sb = kq & 4;
      *(us4*)&sA[0][amt][lane_t][sb] = (us4){h0, h1, h2, h3};
      *(us4*)&sA[1][amt][lane_t][sb] = (us4){l0, l1, l2, l3};
    }
    {
      const float* Brow = Bm + (size_t)(kb + bk) * N + n0g;
#pragma unroll
      for (int i = 0; i < 4; ++i) {
        int n = bnb + i * 32;
        int nt = n >> 4, nr = n & 15;
        float4 b = *(const float4*)(Brow + n);
        float be[4] = {b.x, b.y, b.z, b.w};
#pragma unroll
        for (int e = 0; e < 4; ++e) {
          unsigned short hh, ll;
          split2(be[e], hh, ll);
          sB[0][nt][nr + e + 16 * bg][bslot] = hh;
          sB[1][nt][nr + e + 16 * bg][bslot] = ll;
        }
      }
    }
    __syncthreads();
    if (!activeM) continue;
    bf16x8 ah[4], al[4], bh[4], bl[4];
#pragma unroll
    for (int t = 0; t < 4; ++t) {
      ah[t] = *(const bf16x8*)&sA[0][wr * 4 + t][l][0];
      al[t] = *(const bf16x8*)&sA[1][wr * 4 + t][l][0];
      bh[t] = *(const bf16x8*)&sB[0][wc * 4 + t][l][0];
      bl[t] = *(const bf16x8*)&sB[1][wc * 4 + t][l][0];
    }
#pragma unroll
    for (int mt = 0; mt < 4; ++mt)
#pragma unroll
      for (int nt = 0; nt < 4; ++nt) {
        acc[mt][nt] = __builtin_amdgcn_mfma_f32_16x16x32_bf16(ah[mt], bh[nt], acc[mt][nt], 0, 0, 0);
        acc[mt][nt] = __builtin_amdgcn_mfma_f32_16x16x32_bf16(ah[mt], bl[nt], acc[mt][nt], 0, 0, 0);
        acc[mt][nt] = __builtin_amdgcn_mfma_f32_16x16x32_bf16(al[mt], bh[nt], acc[mt][nt], 0, 0, 0);
      }
  }
  if (!activeM) return;
  float* Cz = C + (size_t)z * mstore * N;
#pragma unroll
  for (int mt = 0; mt < 4; ++mt)
#pragma unroll
    for (int nt = 0; nt < 4; ++nt) {
      int col = n0g + wc * 64 + nt * 16 + (l & 15);
      float badd = bias ? bias[col] : 0.f;
#pragma unroll
      for (int r = 0; r < 4; ++r) {
        int row = m0 + wr * 64 + mt * 16 + ((l >> 4) << 2) + r;
        if (row < mstore) Cz[(size_t)row * N + col] = acc[mt][nt][r] + badd;
      }
    }
}

__global__ __launch_bounds__(64) void k_adj_fb(const float* __restrict__ G,
                                               const float* __restrict__ S,
                                               float* __restrict__ tok) {
  __shared__ float Fm[64][64];
  __shared__ float nrm[64], mm[64];
  int b = blockIdx.x >> 2, lz = blockIdx.x & 3;
  int j = threadIdx.x;
  const float* Gb = G + ((size_t)lz * B16 + b) * 4096;
  const float* Sb = S + ((size_t)lz * B16 + b) * 64;
  float nj = sqrtf(Gb[j * 64 + j]);
  nrm[j] = nj;
  mm[j] = Sb[j] / nj;
  __syncthreads();
  for (int i = 0; i < 64; ++i) {
    float g = Gb[i * 64 + j];
    float sim = g / (nrm[i] * nj);
    float F = mm[i] * mm[j] * sim * sim;
    float v = F;
    bool act = true;
    float kth = 0.f;
#pragma unroll
    for (int it = 0; it < 8; ++it) {
      float mv = wmax64(act ? v : -INFINITY);
      kth = mv;
      unsigned long long ball = __ballot(act && (v == mv));
      int first = __ffsll(ball) - 1;
      if (j == first) act = false;
    }
    float fm = (F >= kth) ? F : 0.f;
    Fm[i][j] = fmaxf(fm, 0.f);
  }
  __syncthreads();
  float* tb = tok + ((size_t)b * 4 + lz) * 4096;
  for (int i = 0; i < 64; ++i) tb[i * 64 + j] = 0.5f * (Fm[i][j] + Fm[j][i]);
}

__global__ __launch_bounds__(256) void k_qkv_reduce(const float* __restrict__ Cp,
                                                    const float* __restrict__ bq,
                                                    const float* __restrict__ bk,
                                                    const float* __restrict__ bv,
                                                    float* __restrict__ q,
                                                    float* __restrict__ k,
                                                    float* __restrict__ v) {
  int idx = blockIdx.x * 256 + threadIdx.x;
  int mat = idx >> 18;
  int rn = idx & ((1 << 18) - 1);
  int n = rn & 4095;
  const float* base = Cp + (size_t)mat * 4 * 262144;
  float s = base[rn] + base[rn + 262144] + base[rn + 2 * 262144] + base[rn + 3 * 262144];
  if (mat == 0) q[rn] = s + bq[n];
  else if (mat == 1) k[rn] = s + bk[n];
  else v[rn] = s + bv[n];
}

__global__ __launch_bounds__(64) void k_attn_fb(const float* __restrict__ q,
                                                const float* __restrict__ k,
                                                const float* __restrict__ v,
                                                float* __restrict__ ctx) {
  int hd = blockIdx.x, b = blockIdx.y;
  int t = threadIdx.x;
  float qr[4][4], kr[4][4], vr[4][4];
#pragma unroll
  for (int l = 0; l < 4; ++l)
#pragma unroll
    for (int s = 0; s < 4; ++s) {
      size_t off = ((size_t)(b * 4 + l)) * 4096 + hd * 256 + t + s * 64;
      qr[l][s] = q[off]; kr[l][s] = k[off]; vr[l][s] = v[off];
    }
  float sc[4][4];
#pragma unroll
  for (int l = 0; l < 4; ++l)
#pragma unroll
    for (int m = 0; m < 4; ++m) {
      float p = 0.f;
#pragma unroll
      for (int s = 0; s < 4; ++s) p = fmaf(qr[l][s], kr[m][s], p);
#pragma unroll
      for (int off = 32; off; off >>= 1) p += __shfl_xor(p, off);
      sc[l][m] = p * (1.0f / 16.0f);
    }
  float at[4][4];
#pragma unroll
  for (int l = 0; l < 4; ++l) {
    float mx = fmaxf(fmaxf(sc[l][0], sc[l][1]), fmaxf(sc[l][2], sc[l][3]));
    float e0 = expf(sc[l][0] - mx), e1 = expf(sc[l][1] - mx);
    float e2 = expf(sc[l][2] - mx), e3 = expf(sc[l][3] - mx);
    float d = e0 + e1 + e2 + e3;
    at[l][0] = e0 / d; at[l][1] = e1 / d; at[l][2] = e2 / d; at[l][3] = e3 / d;
  }
#pragma unroll
  for (int l = 0; l < 4; ++l)
#pragma unroll
    for (int s = 0; s < 4; ++s) {
      float c = 0.f;
#pragma unroll
      for (int m = 0; m < 4; ++m) c = fmaf(at[l][m], vr[m][s], c);
      ctx[((size_t)(b * 4 + l)) * 4096 + hd * 256 + t + s * 64] = c;
    }
}

__global__ __launch_bounds__(256) void k_out_reduce(const float* __restrict__ Cp,
                                                    const float* __restrict__ bo,
                                                    float* __restrict__ out) {
  int idx = blockIdx.x * 256 + threadIdx.x;
  int n = idx & 4095;
  float s = bo[n];
#pragma unroll
  for (int p = 0; p < 8; ++p) s += Cp[(size_t)p * 262144 + idx];
  out[idx] = (s > 0.5f) ? s : 0.f;
}

// ================= launch =================
extern "C" void kernel_launch(void* const* d_in, const int* in_sizes, int n_in,
                              void* d_out, int out_size, void* d_ws, size_t ws_size,
                              hipStream_t stream) {
  const float* x     = (const float*)d_in[0];
  const float* W_mlp = (const float*)d_in[1];
  const float* b_mlp = (const float*)d_in[2];
  const float* Wq = (const float*)d_in[3]; const float* bq = (const float*)d_in[4];
  const float* Wk = (const float*)d_in[5]; const float* bk = (const float*)d_in[6];
  const float* Wv = (const float*)d_in[7]; const float* bv = (const float*)d_in[8];
  const float* Wo = (const float*)d_in[9]; const float* bo = (const float*)d_in[10];
  float* out = (float*)d_out;
  float* ws = (float*)d_ws;

  float* h   = ws;                       // 4,194,304 floats (fallback only)
  float* Gp  = ws + 8388608;             // 32 x 65536 = 2,097,152
  float* Sp  = ws + 10485760;            // 32,768
  float* G   = ws + 10518528;
  float* S   = ws + 10780672;

  const size_t NEED = 50368512ull * 4ull;   // ~202 MB
  if (ws_size >= NEED) {
    // ---------- fast path ----------
    float* q   = ws + 10784768;
    float* kk  = ws + 11046912;
    float* vv  = ws + 11309056;
    unsigned short* AhT = (unsigned short*)(ws + 11571200);   // 4,194,304 shorts
    unsigned short* AlT = (unsigned short*)(ws + 13668352);
    unsigned short* WhT = (unsigned short*)(ws + 15765504);   // 16,777,216 shorts
    unsigned short* WlT = (unsigned short*)(ws + 24154112);
    float* Cp           = ws + 32542720;                      // 16,777,216 floats
    unsigned short* tokh = (unsigned short*)(ws + 49319936);
    unsigned short* tokl = (unsigned short*)(ws + 49582080);
    unsigned short* ctxh = (unsigned short*)(ws + 49844224);
    unsigned short* ctxl = (unsigned short*)(ws + 50106368);  // end 50,368,512 floats

    k_transpose<<<dim3(64, 16), 256, 0, stream>>>(x, h, AhT, AlT, 2);

    // gram slot 0 from AhT/AlT (bs1=2048, ks_stride=4096)
    k_gram_mfma<<<dim3(8, 16), 256, 0, stream>>>(AhT, AlT, Gp, Sp, 2048, 4096, 16);
    k_gred<<<260, 256, 0, stream>>>(Gp, Sp, G, S, 0, 8);

    for (int l = 0; l < 3; ++l) {
      k_wsplit<<<dim3(32, 128), 256, 0, stream>>>(W_mlp + (size_t)l * 16777216, WhT, WlT);
      k_gemm_bf16<<<dim3(32, 8, 2), 512, 0, stream>>>(AhT, AlT, WhT, WlT, Cp,
                                                      128, 2, 4096, 1024);
      k_gram_fuse<<<dim3(32, 16), 256, 0, stream>>>(Cp, b_mlp + (size_t)l * 4096,
                                                    Gp, Sp, 2);
      k_gred<<<260, 256, 0, stream>>>(Gp, Sp, G, S, l + 1, 32);
    }

    k_adj_t<<<64, 256, 0, stream>>>(G, S, tokh, tokl);

    // QKV: one launch, 3 mats x 16 K-splits, W split on-the-fly
    k_gemm_wsf32<<<dim3(32, 1, 48), 512, 0, stream>>>(tokh, tokl, Wq, Wk, Wv, Cp, 16);
    k_redqkv<<<3072, 256, 0, stream>>>(Cp, bq, bk, bv, q, kk, vv);

    k_attn_t<<<dim3(16, 16), 64, 0, stream>>>(q, kk, vv, ctxh, ctxl);

    k_gemm_wsf32<<<dim3(32, 1, 16), 512, 0, stream>>>(ctxh, ctxl, Wo, Wo, Wo, Cp, 16);
    k_redN<<<1024, 256, 0, stream>>>(Cp, bo, out, 16, 1);
  } else {
    // ---------- fallback: round-3 proven path ----------
    float* hv  = ws + 4194304;
    float* tok = ws + 10784768;
    float* q   = ws + 11046912;
    float* kk  = ws + 11309056;
    float* vv  = ws + 11571200;
    float* ctx = ws + 11833344;
    float* qkvp = hv;
    float* op   = h;

    k_transpose<<<dim3(64, 16), 256, 0, stream>>>(x, h, (unsigned short*)0,
                                                  (unsigned short*)0, 0);
    k_gram_partial<<<dim3(NCHUNK, 16), 256, 0, stream>>>(h, Gp, Sp);
    k_gram_reduce<<<260, 256, 0, stream>>>(Gp, Sp, G, S, 0);
    for (int l = 0; l < 3; ++l) {
      const float* Wl = W_mlp + (size_t)l * PDIM * 4096;
      const float* bl = b_mlp + (size_t)l * 4096;
      k_gemm_mfma<<<dim3(32, 8, 1), 256, 0, stream>>>(h, Wl, Wl, Wl, bl, hv,
                                                      1024, 1024, 4096, 4096, 1);
      k_gram_partial<<<dim3(NCHUNK, 16), 256, 0, stream>>>(hv, Gp, Sp);
      k_gram_reduce<<<260, 256, 0, stream>>>(Gp, Sp, G, S, l + 1);
    }
    k_adj_fb<<<64, 64, 0, stream>>>(G, S, tok);
    k_gemm_mfma<<<dim3(32, 1, 12), 256, 0, stream>>>(tok, Wq, Wk, Wv, nullptr, qkvp,
                                                     64, 64, 4096, 4096, 4);
    k_qkv_reduce<<<3072, 256, 0, stream>>>(qkvp, bq, bk, bv, q, kk, vv);
    k_attn_fb<<<dim3(16, 16), 64, 0, stream>>>(q, kk, vv, ctx);
    k_gemm_mfma<<<dim3(32, 1, 8), 256, 0, stream>>>(ctx, Wo, Wo, Wo, nullptr, op,
                                                    64, 64, 4096, 4096, 8);
    k_out_reduce<<<1024, 256, 0, stream>>>(op, bo, out);
  }
}

// Round 18
// 557.626 us; speedup vs baseline: 1.4304x; 1.4304x over previous
//
#include <hip/hip_runtime.h>
#include <math.h>

// GraphStructureLearning: B=16, P=4096, DM=N=64, NLAYER=3, HID=4096, NH=16, dh=256, L=4.
// Round 18: REVERT to round-15 best (557.9us). Round-17 no-LDS GEMM was L2-bound
// (172us, VALUBusy 7.8%): LDS staging is the de-duplication mechanism, not overhead.
// The 2-barrier split-GEMM family is at its balanced optimum (~108us/GEMM); all
// structural levers (tile/occupancy/vmcnt/phases/no-LDS) measured null or worse.

#define B16 16
#define PDIM 4096
#define NNODE 64
#define NCHUNK 32
#define KCG 128

typedef __attribute__((ext_vector_type(8))) short bf16x8;
typedef __attribute__((ext_vector_type(4))) float f32x4;
typedef __attribute__((ext_vector_type(4))) unsigned short us4;
typedef __attribute__((ext_vector_type(8))) unsigned short us8;

// f32 -> (hi bf16, lo bf16), RNE both; x ~ hi + lo with |err| <= 2^-18 |x|.
__device__ inline void split2(float x, unsigned short& h, unsigned short& l) {
  unsigned u = __float_as_uint(x);
  unsigned hu = (u + 0x7fffu + ((u >> 16) & 1u)) & 0xffff0000u;
  h = (unsigned short)(hu >> 16);
  float lo = x - __uint_as_float(hu);
  unsigned u2 = __float_as_uint(lo);
  l = (unsigned short)((u2 + 0x7fffu + ((u2 >> 16) & 1u)) >> 16);
}

__device__ inline void gload16(const void* g, void* lds) {
  __builtin_amdgcn_global_load_lds((const unsigned int*)g, (unsigned int*)lds, 16, 0, 0);
}

// ---------------- transpose x[B][4096][64] -> tiled split A (and f32 h for fallback) --
__global__ __launch_bounds__(256) void k_transpose(const float* __restrict__ x,
                                                   float* __restrict__ h,
                                                   unsigned short* __restrict__ AhT,
                                                   unsigned short* __restrict__ AlT,
                                                   int mode) {
  __shared__ float t[64][65];
  int b = blockIdx.y;
  int p0 = blockIdx.x * 64;
  const float* xb = x + (size_t)b * PDIM * NNODE;
#pragma unroll
  for (int i = 0; i < 16; ++i) {
    int e = i * 256 + threadIdx.x;
    int p = e >> 6, n = e & 63;
    t[p][n] = xb[(size_t)p0 * 64 + e];
  }
  __syncthreads();
  if (mode != 2) {
    float* hb = h + (size_t)b * NNODE * PDIM;
#pragma unroll
    for (int i = 0; i < 16; ++i) {
      int e = i * 256 + threadIdx.x;
      int n = e >> 6, p = e & 63;
      hb[(size_t)n * PDIM + p0 + p] = t[p][n];
    }
  }
  if (mode == 0) return;
#pragma unroll
  for (int j = 0; j < 2; ++j) {
    int cid = j * 256 + threadIdx.x;    // 512 cells: 64 n x 8 k-groups
    int n2 = cid >> 3, kg8 = cid & 7;
    us8 hv_, lv_;
#pragma unroll
    for (int e = 0; e < 8; ++e) {
      unsigned short hh, ll;
      split2(t[kg8 * 8 + e][n2], hh, ll);
      hv_[e] = hh; lv_[e] = ll;
    }
    int m = b * 64 + n2;
    int ks = (p0 >> 5) + (kg8 >> 2);
    size_t idx = (((size_t)(m >> 7) * 128 + ks) * 8 + ((m >> 4) & 7)) * 512 +
                 (size_t)((n2 & 15) + 16 * (kg8 & 3)) * 8;
    *(us8*)&AhT[idx] = hv_;
    *(us8*)&AlT[idx] = lv_;
  }
}

// ---------------- weight split+tile (MLP only): W[4096][4096] f32 -> WhT/WlT --------
__global__ __launch_bounds__(256) void k_wsplit(const float* __restrict__ W,
                                                unsigned short* __restrict__ WhT,
                                                unsigned short* __restrict__ WlT) {
  __shared__ float Wt[32][132];
  int nb = blockIdx.x, kb = blockIdx.y;
  int tid = threadIdx.x;
#pragma unroll
  for (int i = 0; i < 4; ++i) {
    int idx = i * 256 + tid;
    int row = idx >> 5, c4 = idx & 31;
    float4 v = *(const float4*)&W[(size_t)(kb * 32 + row) * 4096 + nb * 128 + c4 * 4];
    *(float4*)&Wt[row][c4 * 4] = v;
  }
  __syncthreads();
#pragma unroll
  for (int j = 0; j < 2; ++j) {
    int cid = j * 256 + tid;            // 512 cells: 128 n x 4 k-groups
    int nl = cid & 127, kg = cid >> 7;
    us8 hv_, lv_;
#pragma unroll
    for (int e = 0; e < 8; ++e) {
      unsigned short hh, ll;
      split2(Wt[kg * 8 + e][nl], hh, ll);
      hv_[e] = hh; lv_[e] = ll;
    }
    size_t idx = (((size_t)nb * 128 + kb) * 8 + (nl >> 4)) * 512 +
                 (size_t)((nl & 15) + 16 * kg) * 8;
    *(us8*)&WhT[idx] = hv_;
    *(us8*)&WlT[idx] = lv_;
  }
}

// ---------------- MLP bf16 GEMM: counted-vmcnt depth-2 pipeline ----------------
// BM=128 BN=128 BK=32, grid (nb=32, mb=8, z=2); 512 thr = 8 waves (2wr x 4wc);
// 64 KB LDS -> 2 blocks/CU. Prologue stages tiles 0,1 (8 gloads); per iter:
// vmcnt(4) keeps next tile's 4 loads in flight across the barrier; issue t+2 after.
__global__ __launch_bounds__(512) void k_gemm_bf16(
    const unsigned short* __restrict__ Ah, const unsigned short* __restrict__ Al,
    const unsigned short* __restrict__ Bh, const unsigned short* __restrict__ Bl,
    float* __restrict__ Cp, int Ksteps, int ksplit, int N, int mstore) {
  __shared__ unsigned short sAh[2][4096], sAl[2][4096];
  __shared__ unsigned short sBh[2][4096], sBl[2][4096];   // 64 KB
  int tid = threadIdx.x;
  int l = tid & 63, wid = tid >> 6;
  int wr = wid >> 2, wc = wid & 3;
  int nb = blockIdx.x, mb = blockIdx.y, z = blockIdx.z;
  int spp = Ksteps / ksplit;
  int ks0 = z * spp;

  const size_t abase = ((size_t)mb * Ksteps + ks0) * 4096 + tid * 8;
  const size_t bbase = ((size_t)nb * Ksteps + ks0) * 4096 + tid * 8;

  f32x4 acc[4][2];
#pragma unroll
  for (int i = 0; i < 4; ++i)
#pragma unroll
    for (int j = 0; j < 2; ++j) acc[i][j] = (f32x4){0.f, 0.f, 0.f, 0.f};

  // prologue: stage tiles 0 and 1 (8 gloads/thread outstanding)
  gload16(Ah + abase, &sAh[0][tid * 8]);
  gload16(Al + abase, &sAl[0][tid * 8]);
  gload16(Bh + bbase, &sBh[0][tid * 8]);
  gload16(Bl + bbase, &sBl[0][tid * 8]);
  gload16(Ah + abase + 4096, &sAh[1][tid * 8]);
  gload16(Al + abase + 4096, &sAl[1][tid * 8]);
  gload16(Bh + bbase + 4096, &sBh[1][tid * 8]);
  gload16(Bl + bbase + 4096, &sBl[1][tid * 8]);

  for (int t = 0; t < spp; ++t) {
    int buf = t & 1;
    if (t + 1 < spp) asm volatile("s_waitcnt vmcnt(4)" ::: "memory");
    else             asm volatile("s_waitcnt vmcnt(0)" ::: "memory");
    __builtin_amdgcn_s_barrier();       // all waves' tile-t loads landed
    asm volatile("" ::: "memory");

    bf16x8 ah[4], al4[4], bh2[2], bl2[2];
#pragma unroll
    for (int mt = 0; mt < 4; ++mt) {
      ah[mt]  = *(const bf16x8*)&sAh[buf][(wr * 4 + mt) * 512 + l * 8];
      al4[mt] = *(const bf16x8*)&sAl[buf][(wr * 4 + mt) * 512 + l * 8];
    }
#pragma unroll
    for (int nt = 0; nt < 2; ++nt) {
      bh2[nt] = *(const bf16x8*)&sBh[buf][(wc * 2 + nt) * 512 + l * 8];
      bl2[nt] = *(const bf16x8*)&sBl[buf][(wc * 2 + nt) * 512 + l * 8];
    }
#pragma unroll
    for (int mt = 0; mt < 4; ++mt)
#pragma unroll
      for (int nt = 0; nt < 2; ++nt) {
        acc[mt][nt] = __builtin_amdgcn_mfma_f32_16x16x32_bf16(ah[mt],  bh2[nt], acc[mt][nt], 0, 0, 0);
        acc[mt][nt] = __builtin_amdgcn_mfma_f32_16x16x32_bf16(ah[mt],  bl2[nt], acc[mt][nt], 0, 0, 0);
        acc[mt][nt] = __builtin_amdgcn_mfma_f32_16x16x32_bf16(al4[mt], bh2[nt], acc[mt][nt], 0, 0, 0);
      }

    asm volatile("" ::: "memory");
    __builtin_amdgcn_s_barrier();       // all waves done reading buf
    asm volatile("" ::: "memory");
    if (t + 2 < spp) {
      size_t off = (size_t)(t + 2) * 4096;
      gload16(Ah + abase + off, &sAh[buf][tid * 8]);
      gload16(Al + abase + off, &sAl[buf][tid * 8]);
      gload16(Bh + bbase + off, &sBh[buf][tid * 8]);
      gload16(Bl + bbase + off, &sBl[buf][tid * 8]);
    }
  }

  int n0 = nb * 128, m0 = mb * 128;
  float* Cz = Cp + (size_t)z * mstore * N;
#pragma unroll
  for (int mt = 0; mt < 4; ++mt)
#pragma unroll
    for (int nt = 0; nt < 2; ++nt) {
      int col = n0 + wc * 32 + nt * 16 + (l & 15);
#pragma unroll
      for (int r = 0; r < 4; ++r) {
        int row = m0 + wr * 64 + mt * 16 + ((l >> 4) << 2) + r;
        if (row < mstore) Cz[(size_t)row * N + col] = acc[mt][nt][r];
      }
    }
}

// ---------------- QKV/O GEMM: A pre-tiled (rows 0..63), W split on-the-fly ----------
__global__ __launch_bounds__(512) void k_gemm_wsf32(
    const unsigned short* __restrict__ Ah, const unsigned short* __restrict__ Al,
    const float* __restrict__ W0, const float* __restrict__ W1,
    const float* __restrict__ W2, float* __restrict__ Cp, int ksplit) {
  __shared__ unsigned short sAh[2][2048], sAl[2][2048];   // 16 KB
  __shared__ unsigned short sBh[2][4096], sBl[2][4096];   // 32 KB
  int tid = threadIdx.x;
  int l = tid & 63, wid = tid >> 6;
  int wr = wid >> 2, wc = wid & 3;
  int nb = blockIdx.x, z = blockIdx.z;
  int mat = z / ksplit, kz = z - mat * ksplit;
  const float* W = (mat == 0) ? W0 : ((mat == 1) ? W1 : W2);
  int nsteps = 128 / ksplit;
  int ks0 = kz * nsteps;
  int n0 = nb * 128;

  const float* wbase = W + (size_t)((l >> 4) * 8) * 4096 + n0 + wid * 16 + (l & 15);
  int sidx = wid * 512 + l * 8;

  f32x4 acc[2][2];
#pragma unroll
  for (int i = 0; i < 2; ++i)
#pragma unroll
    for (int j = 0; j < 2; ++j) acc[i][j] = (f32x4){0.f, 0.f, 0.f, 0.f};

  {
    if (tid < 256) gload16(Ah + (size_t)ks0 * 4096 + tid * 8, &sAh[0][tid * 8]);
    else           gload16(Al + (size_t)ks0 * 4096 + (tid - 256) * 8, &sAl[0][(tid - 256) * 8]);
    float wv[8];
#pragma unroll
    for (int e = 0; e < 8; ++e) wv[e] = wbase[(size_t)ks0 * 131072 + (size_t)e * 4096];
    us8 hi, lo;
#pragma unroll
    for (int e = 0; e < 8; ++e) {
      unsigned short hh, ll;
      split2(wv[e], hh, ll);
      hi[e] = hh; lo[e] = ll;
    }
    *(us8*)&sBh[0][sidx] = hi;
    *(us8*)&sBl[0][sidx] = lo;
  }
  __syncthreads();

  int buf = 0;
  for (int t = 0; t < nsteps; ++t) {
    bool more = (t + 1 < nsteps);
    float wv[8];
    if (more) {
      int ks = ks0 + t + 1;
      if (tid < 256) gload16(Ah + (size_t)ks * 4096 + tid * 8, &sAh[buf ^ 1][tid * 8]);
      else           gload16(Al + (size_t)ks * 4096 + (tid - 256) * 8, &sAl[buf ^ 1][(tid - 256) * 8]);
#pragma unroll
      for (int e = 0; e < 8; ++e) wv[e] = wbase[(size_t)ks * 131072 + (size_t)e * 4096];
    }
    bf16x8 aH[2], aL[2], bH[2], bL[2];
#pragma unroll
    for (int i = 0; i < 2; ++i) {
      aH[i] = *(const bf16x8*)&sAh[buf][(wr * 2 + i) * 512 + l * 8];
      aL[i] = *(const bf16x8*)&sAl[buf][(wr * 2 + i) * 512 + l * 8];
      bH[i] = *(const bf16x8*)&sBh[buf][(wc * 2 + i) * 512 + l * 8];
      bL[i] = *(const bf16x8*)&sBl[buf][(wc * 2 + i) * 512 + l * 8];
    }
#pragma unroll
    for (int i = 0; i < 2; ++i)
#pragma unroll
      for (int j = 0; j < 2; ++j) {
        acc[i][j] = __builtin_amdgcn_mfma_f32_16x16x32_bf16(aH[i], bH[j], acc[i][j], 0, 0, 0);
        acc[i][j] = __builtin_amdgcn_mfma_f32_16x16x32_bf16(aH[i], bL[j], acc[i][j], 0, 0, 0);
        acc[i][j] = __builtin_amdgcn_mfma_f32_16x16x32_bf16(aL[i], bH[j], acc[i][j], 0, 0, 0);
      }
    if (more) {
      us8 hi, lo;
#pragma unroll
      for (int e = 0; e < 8; ++e) {
        unsigned short hh, ll;
        split2(wv[e], hh, ll);
        hi[e] = hh; lo[e] = ll;
      }
      *(us8*)&sBh[buf ^ 1][sidx] = hi;
      *(us8*)&sBl[buf ^ 1][sidx] = lo;
    }
    __syncthreads();
    buf ^= 1;
  }

  float* Cz = Cp + (size_t)z * 262144;
#pragma unroll
  for (int i = 0; i < 2; ++i)
#pragma unroll
    for (int j = 0; j < 2; ++j) {
      int col = n0 + wc * 32 + j * 16 + (l & 15);
#pragma unroll
      for (int r = 0; r < 4; ++r) {
        int row = (wr * 2 + i) * 16 + ((l >> 4) << 2) + r;
        Cz[(size_t)row * 4096 + col] = acc[i][j][r];
      }
    }
}

// ---------------- fused gram: reduce(Cp)+bias -> split -> tile -> MFMA ----------------
// grid (zk=32, b=16) -> 512 blocks (2/CU). 4 steps of k-chunk 32.
__global__ __launch_bounds__(256) void k_gram_fuse(
    const float* __restrict__ Cp, const float* __restrict__ bias,
    float* __restrict__ Gp, float* __restrict__ Sp, int nparts) {
  __shared__ unsigned short sZh[2048], sZl[2048];
  int zk = blockIdx.x, b = blockIdx.y;
  int tid = threadIdx.x;
  int l = tid & 63, w = tid >> 6;
  int srow = tid >> 2, skq = tid & 3;
  const float* cbase = Cp + (size_t)(b * 64 + srow) * 4096;
  int swidx = (srow >> 4) * 512 + (skq * 16 + (srow & 15)) * 8;

  f32x4 acc[4], racc;
#pragma unroll
  for (int j = 0; j < 4; ++j) acc[j] = (f32x4){0.f, 0.f, 0.f, 0.f};
  racc = (f32x4){0.f, 0.f, 0.f, 0.f};
  bf16x8 ones;
#pragma unroll
  for (int e = 0; e < 8; ++e) ones[e] = (short)0x3F80;    // bf16 1.0

  for (int s = 0; s < 4; ++s) {
    int k0 = zk * 128 + s * 32 + skq * 8;
    float v[8];
#pragma unroll
    for (int e = 0; e < 8; ++e) v[e] = bias[k0 + e];
    for (int p = 0; p < nparts; ++p) {
      const float* pp = cbase + (size_t)p * 4194304 + k0;
      float4 a0 = *(const float4*)pp;
      float4 a1 = *(const float4*)(pp + 4);
      v[0] += a0.x; v[1] += a0.y; v[2] += a0.z; v[3] += a0.w;
      v[4] += a1.x; v[5] += a1.y; v[6] += a1.z; v[7] += a1.w;
    }
    us8 hi, lo;
#pragma unroll
    for (int e = 0; e < 8; ++e) {
      unsigned short hh, ll;
      split2(v[e], hh, ll);
      hi[e] = hh; lo[e] = ll;
    }
    *(us8*)&sZh[swidx] = hi;
    *(us8*)&sZl[swidx] = lo;
    __syncthreads();
    bf16x8 bh[4], bl4[4];
#pragma unroll
    for (int nt = 0; nt < 4; ++nt) {
      bh[nt]  = *(const bf16x8*)&sZh[nt * 512 + l * 8];
      bl4[nt] = *(const bf16x8*)&sZl[nt * 512 + l * 8];
    }
    bf16x8 ah = bh[w], al = bl4[w];
#pragma unroll
    for (int nt = 0; nt < 4; ++nt) {
      acc[nt] = __builtin_amdgcn_mfma_f32_16x16x32_bf16(ah, bh[nt], acc[nt], 0, 0, 0);
      acc[nt] = __builtin_amdgcn_mfma_f32_16x16x32_bf16(ah, bl4[nt], acc[nt], 0, 0, 0);
      acc[nt] = __builtin_amdgcn_mfma_f32_16x16x32_bf16(al, bh[nt], acc[nt], 0, 0, 0);
    }
    racc = __builtin_amdgcn_mfma_f32_16x16x32_bf16(ah, ones, racc, 0, 0, 0);
    racc = __builtin_amdgcn_mfma_f32_16x16x32_bf16(al, ones, racc, 0, 0, 0);
    __syncthreads();
  }

  float* Gz = Gp + ((size_t)zk * B16 + b) * 4096;
#pragma unroll
  for (int nt = 0; nt < 4; ++nt) {
    int col = nt * 16 + (l & 15);
#pragma unroll
    for (int r = 0; r < 4; ++r) {
      int row = w * 16 + ((l >> 4) << 2) + r;
      Gz[row * 64 + col] = acc[nt][r];
    }
  }
  if ((l & 15) == 0) {
    float* Sz = Sp + ((size_t)zk * B16 + b) * 64;
#pragma unroll
    for (int r = 0; r < 4; ++r) Sz[w * 16 + ((l >> 4) << 2) + r] = racc[r];
  }
}

// ---------------- gram via MFMA on pre-split tiles (slot 0) ----------------
__global__ __launch_bounds__(256) void k_gram_mfma(
    const unsigned short* __restrict__ Zh, const unsigned short* __restrict__ Zl,
    float* __restrict__ Gp, float* __restrict__ Sp,
    int bs1, int ks_stride, int nsteps) {
  __shared__ unsigned short sZh[2][2048], sZl[2][2048];
  int z = blockIdx.x, b = blockIdx.y;
  int tid = threadIdx.x;
  int l = tid & 63, w = tid >> 6;
  size_t zbase = (size_t)(b >> 1) * 524288 + (size_t)(b & 1) * bs1;
  int ks0 = z * nsteps;

  f32x4 acc[4], racc;
#pragma unroll
  for (int j = 0; j < 4; ++j) acc[j] = (f32x4){0.f, 0.f, 0.f, 0.f};
  racc = (f32x4){0.f, 0.f, 0.f, 0.f};
  bf16x8 ones;
#pragma unroll
  for (int e = 0; e < 8; ++e) ones[e] = (short)0x3F80;

  gload16(Zh + zbase + (size_t)ks0 * ks_stride + tid * 8, &sZh[0][tid * 8]);
  gload16(Zl + zbase + (size_t)ks0 * ks_stride + tid * 8, &sZl[0][tid * 8]);
  __syncthreads();

  int buf = 0;
  for (int t = 0; t < nsteps; ++t) {
    if (t + 1 < nsteps) {
      size_t off = zbase + (size_t)(ks0 + t + 1) * ks_stride + tid * 8;
      gload16(Zh + off, &sZh[buf ^ 1][tid * 8]);
      gload16(Zl + off, &sZl[buf ^ 1][tid * 8]);
    }
    bf16x8 bh[4], bl4[4];
#pragma unroll
    for (int nt = 0; nt < 4; ++nt) {
      bh[nt]  = *(const bf16x8*)&sZh[buf][nt * 512 + l * 8];
      bl4[nt] = *(const bf16x8*)&sZl[buf][nt * 512 + l * 8];
    }
    bf16x8 ah = bh[w], al = bl4[w];
#pragma unroll
    for (int nt = 0; nt < 4; ++nt) {
      acc[nt] = __builtin_amdgcn_mfma_f32_16x16x32_bf16(ah, bh[nt], acc[nt], 0, 0, 0);
      acc[nt] = __builtin_amdgcn_mfma_f32_16x16x32_bf16(ah, bl4[nt], acc[nt], 0, 0, 0);
      acc[nt] = __builtin_amdgcn_mfma_f32_16x16x32_bf16(al, bh[nt], acc[nt], 0, 0, 0);
    }
    racc = __builtin_amdgcn_mfma_f32_16x16x32_bf16(ah, ones, racc, 0, 0, 0);
    racc = __builtin_amdgcn_mfma_f32_16x16x32_bf16(al, ones, racc, 0, 0, 0);
    __syncthreads();
    buf ^= 1;
  }

  float* Gz = Gp + ((size_t)z * B16 + b) * 4096;
#pragma unroll
  for (int nt = 0; nt < 4; ++nt) {
    int col = nt * 16 + (l & 15);
#pragma unroll
    for (int r = 0; r < 4; ++r) {
      int row = w * 16 + ((l >> 4) << 2) + r;
      Gz[row * 64 + col] = acc[nt][r];
    }
  }
  if ((l & 15) == 0) {
    float* Sz = Sp + ((size_t)z * B16 + b) * 64;
#pragma unroll
    for (int r = 0; r < 4; ++r) Sz[w * 16 + ((l >> 4) << 2) + r] = racc[r];
  }
}

// ---------------- gram partial reduce (nc chunks) ----------------
__global__ __launch_bounds__(256) void k_gred(const float* __restrict__ Gp,
                                              const float* __restrict__ Sp,
                                              float* __restrict__ G,
                                              float* __restrict__ S, int slot, int nc) {
  int idx = blockIdx.x * 256 + threadIdx.x;
  if (idx < 65536) {
    float s = 0.f;
    for (int c = 0; c < nc; ++c) s += Gp[(size_t)c * 65536 + idx];
    G[(size_t)slot * 65536 + idx] = s;
  } else if (idx < 66560) {
    int i2 = idx - 65536;
    float s = 0.f;
    for (int c = 0; c < nc; ++c) s += Sp[(size_t)c * 1024 + i2];
    S[(size_t)slot * 1024 + i2] = s;
  }
}

// ---------------- QKV reduce (16 partials each), one launch ----------------
__global__ __launch_bounds__(256) void k_redqkv(const float* __restrict__ Cp,
                                                const float* __restrict__ bq,
                                                const float* __restrict__ bk,
                                                const float* __restrict__ bv,
                                                float* __restrict__ q,
                                                float* __restrict__ k,
                                                float* __restrict__ v) {
  int idx = blockIdx.x * 256 + threadIdx.x;   // 3 * 262144
  int mat = idx >> 18;
  int rn = idx & ((1 << 18) - 1);
  int n = rn & 4095;
  const float* base = Cp + (size_t)mat * 16 * 262144;
  float s = 0.f;
#pragma unroll
  for (int p = 0; p < 16; ++p) s += base[(size_t)p * 262144 + rn];
  if (mat == 0) q[rn] = s + bq[n];
  else if (mat == 1) k[rn] = s + bk[n];
  else v[rn] = s + bv[n];
}

// ---------------- generic partial reduce + bias (+threshold) ----------------
__global__ __launch_bounds__(256) void k_redN(const float* __restrict__ Cp,
                                              const float* __restrict__ bias,
                                              float* __restrict__ dst,
                                              int nparts, int thr) {
  int idx = blockIdx.x * 256 + threadIdx.x;   // 262,144
  float s = bias[idx & 4095];
  for (int p = 0; p < nparts; ++p) s += Cp[(size_t)p * 262144 + idx];
  if (thr) s = (s > 0.5f) ? s : 0.f;
  dst[idx] = s;
}

__device__ inline float wmax64(float v) {
#pragma unroll
  for (int off = 32; off; off >>= 1) v = fmaxf(v, __shfl_xor(v, off));
  return v;
}

// ---------------- adjacency: rank-based top-8, 256 threads ----------------
__global__ __launch_bounds__(256) void k_adj_t(const float* __restrict__ G,
                                               const float* __restrict__ S,
                                               unsigned short* __restrict__ tokh,
                                               unsigned short* __restrict__ tokl) {
  __shared__ float Fm[64][64];
  __shared__ float nrm[64], mm[64];
  int b = blockIdx.x >> 2, lz = blockIdx.x & 3;
  int tid = threadIdx.x;
  int j = tid & 63, w = tid >> 6;
  const float* Gb = G + ((size_t)lz * B16 + b) * 4096;
  const float* Sb = S + ((size_t)lz * B16 + b) * 64;
  if (tid < 64) {
    float nj = sqrtf(Gb[tid * 64 + tid]);
    nrm[tid] = nj;
    mm[tid] = Sb[tid] / nj;
  }
  __syncthreads();
  for (int i = w; i < 64; i += 4) {
    float g = Gb[i * 64 + j];
    float sim = g / (nrm[i] * nrm[j]);
    Fm[i][j] = mm[i] * mm[j] * sim * sim;
  }
  __syncthreads();
  for (int i = w; i < 64; i += 4) {
    float f = Fm[i][j];
    int cnt = 0;
#pragma unroll
    for (int u4 = 0; u4 < 16; ++u4) {
      float4 q = *(const float4*)&Fm[i][u4 * 4];
      cnt += (q.x > f) + (q.y > f) + (q.z > f) + (q.w > f);
    }
    float cand = (cnt <= 7) ? f : INFINITY;
#pragma unroll
    for (int off = 32; off; off >>= 1) cand = fminf(cand, __shfl_xor(cand, off));
    float fm = (f >= cand) ? fmaxf(f, 0.f) : 0.f;
    Fm[i][j] = fm;
  }
  __syncthreads();
  int r = b * 4 + lz;
  int mt = r >> 4, rl = r & 15;
#pragma unroll
  for (int c = 0; c < 2; ++c) {
    int cid = tid * 2 + c;
    int jj0 = cid >> 3, g = cid & 7;
    us8 hv_, lv_;
#pragma unroll
    for (int e = 0; e < 8; ++e) {
      int kcol = g * 8 + e;
      float val = 0.5f * (Fm[jj0][kcol] + Fm[kcol][jj0]);
      unsigned short hh, ll;
      split2(val, hh, ll);
      hv_[e] = hh; lv_[e] = ll;
    }
    int ks = jj0 * 2 + (g >> 2);
    size_t idx = ((size_t)ks * 8 + mt) * 512 + (size_t)(rl + 16 * (g & 3)) * 8;
    *(us8*)&tokh[idx] = hv_;
    *(us8*)&tokl[idx] = lv_;
  }
}

// ---------------- attention, tiled split ctx output ----------------
__global__ __launch_bounds__(64) void k_attn_t(const float* __restrict__ q,
                                               const float* __restrict__ k,
                                               const float* __restrict__ v,
                                               unsigned short* __restrict__ ctxh,
                                               unsigned short* __restrict__ ctxl) {
  __shared__ float cb[4][256];
  int hd = blockIdx.x, b = blockIdx.y;
  int t = threadIdx.x;
  float qr[4][4], kr[4][4], vr[4][4];
#pragma unroll
  for (int l = 0; l < 4; ++l)
#pragma unroll
    for (int s = 0; s < 4; ++s) {
      size_t off = ((size_t)(b * 4 + l)) * 4096 + hd * 256 + t + s * 64;
      qr[l][s] = q[off]; kr[l][s] = k[off]; vr[l][s] = v[off];
    }
  float sc[4][4];
#pragma unroll
  for (int l = 0; l < 4; ++l)
#pragma unroll
    for (int m = 0; m < 4; ++m) {
      float p = 0.f;
#pragma unroll
      for (int s = 0; s < 4; ++s) p = fmaf(qr[l][s], kr[m][s], p);
#pragma unroll
      for (int off = 32; off; off >>= 1) p += __shfl_xor(p, off);
      sc[l][m] = p * (1.0f / 16.0f);
    }
  float at[4][4];
#pragma unroll
  for (int l = 0; l < 4; ++l) {
    float mx = fmaxf(fmaxf(sc[l][0], sc[l][1]), fmaxf(sc[l][2], sc[l][3]));
    float e0 = expf(sc[l][0] - mx), e1 = expf(sc[l][1] - mx);
    float e2 = expf(sc[l][2] - mx), e3 = expf(sc[l][3] - mx);
    float d = e0 + e1 + e2 + e3;
    at[l][0] = e0 / d; at[l][1] = e1 / d; at[l][2] = e2 / d; at[l][3] = e3 / d;
  }
#pragma unroll
  for (int l = 0; l < 4; ++l)
#pragma unroll
    for (int s = 0; s < 4; ++s) {
      float c = 0.f;
#pragma unroll
      for (int m = 0; m < 4; ++m) c = fmaf(at[l][m], vr[m][s], c);
      cb[l][s * 64 + t] = c;
    }
  __syncthreads();
  int lq = t >> 4, c16 = t & 15;
  int mt = b >> 2, rl = (b & 3) * 4 + lq;
#pragma unroll
  for (int e8 = 0; e8 < 2; ++e8) {
    us8 hv_, lv_;
#pragma unroll
    for (int e = 0; e < 8; ++e) {
      unsigned short hh, ll;
      split2(cb[lq][c16 * 16 + e8 * 8 + e], hh, ll);
      hv_[e] = hh; lv_[e] = ll;
    }
    int ks = hd * 8 + (c16 >> 1);
    size_t idx = ((size_t)ks * 8 + mt) * 512 + (size_t)(rl + 16 * ((c16 * 2 + e8) & 3)) * 8;
    *(us8*)&ctxh[idx] = hv_;
    *(us8*)&ctxl[idx] = lv_;
  }
}

// ================= FALLBACK (round-3 proven path) =================
__global__ __launch_bounds__(256) void k_gram_partial(const float* __restrict__ Z,
                                                      float* __restrict__ Gp,
                                                      float* __restrict__ Sp) {
  __shared__ float Zt[KCG][68];
  int c = blockIdx.x, b = blockIdx.y;
  int tid = threadIdx.x;
  const float* Zb = Z + (size_t)b * NNODE * PDIM + c * KCG;
#pragma unroll
  for (int i = 0; i < 32; ++i) {
    int e = i * 256 + tid;
    int r = e >> 7, kk = e & 127;
    Zt[kk][r] = Zb[(size_t)r * PDIM + kk];
  }
  __syncthreads();
  int ii = tid >> 2, j0 = (tid & 3) << 4;
  float acc[16] = {};
  for (int kk = 0; kk < KCG; ++kk) {
    float zi = Zt[kk][ii];
    float4 z0 = *(const float4*)&Zt[kk][j0 + 0];
    float4 z1 = *(const float4*)&Zt[kk][j0 + 4];
    float4 z2 = *(const float4*)&Zt[kk][j0 + 8];
    float4 z3 = *(const float4*)&Zt[kk][j0 + 12];
    acc[0] = fmaf(zi, z0.x, acc[0]);   acc[1] = fmaf(zi, z0.y, acc[1]);
    acc[2] = fmaf(zi, z0.z, acc[2]);   acc[3] = fmaf(zi, z0.w, acc[3]);
    acc[4] = fmaf(zi, z1.x, acc[4]);   acc[5] = fmaf(zi, z1.y, acc[5]);
    acc[6] = fmaf(zi, z1.z, acc[6]);   acc[7] = fmaf(zi, z1.w, acc[7]);
    acc[8] = fmaf(zi, z2.x, acc[8]);   acc[9] = fmaf(zi, z2.y, acc[9]);
    acc[10] = fmaf(zi, z2.z, acc[10]); acc[11] = fmaf(zi, z2.w, acc[11]);
    acc[12] = fmaf(zi, z3.x, acc[12]); acc[13] = fmaf(zi, z3.y, acc[13]);
    acc[14] = fmaf(zi, z3.z, acc[14]); acc[15] = fmaf(zi, z3.w, acc[15]);
  }
  float* gp = Gp + ((size_t)c * B16 + b) * 4096 + ii * 64 + j0;
#pragma unroll
  for (int j = 0; j < 16; ++j) gp[j] = acc[j];
  if (tid < 64) {
    float s = 0.f;
    for (int kk = 0; kk < KCG; ++kk) s += Zt[kk][tid];
    Sp[((size_t)c * B16 + b) * 64 + tid] = s;
  }
}

__global__ __launch_bounds__(256) void k_gram_reduce(const float* __restrict__ Gp,
                                                     const float* __restrict__ Sp,
                                                     float* __restrict__ G,
                                                     float* __restrict__ S, int slot) {
  int idx = blockIdx.x * 256 + threadIdx.x;
  if (idx < B16 * 4096) {
    float s = 0.f;
    for (int c = 0; c < NCHUNK; ++c) s += Gp[(size_t)c * (B16 * 4096) + idx];
    G[(size_t)slot * (B16 * 4096) + idx] = s;
  } else {
    int idx2 = idx - B16 * 4096;
    float s = 0.f;
    for (int c = 0; c < NCHUNK; ++c) s += Sp[(size_t)c * (B16 * 64) + idx2];
    S[(size_t)slot * (B16 * 64) + idx2] = s;
  }
}

__global__ __launch_bounds__(256) void k_gemm_mfma(
    const float* __restrict__ A, const float* __restrict__ B0,
    const float* __restrict__ B1, const float* __restrict__ B2,
    const float* __restrict__ bias, float* __restrict__ C,
    int mrows, int mstore, int N, int K, int ksplit) {
  __shared__ __align__(16) unsigned short sA[2][8][64][8];
  __shared__ __align__(16) unsigned short sB[2][8][64][8];
  int z = blockIdx.z;
  int mat = z / ksplit, ks = z - mat * ksplit;
  const float* Bm = (mat == 0) ? B0 : ((mat == 1) ? B1 : B2);
  int kchunk = K / ksplit;
  int k0 = ks * kchunk, k1 = k0 + kchunk;
  int tid = threadIdx.x;
  int l = tid & 63;
  int wr = (tid >> 7) & 1, wc = (tid >> 6) & 1;
  int m0 = blockIdx.y * 128, n0g = blockIdx.x * 128;
  bool activeM = (m0 + wr * 64) < mstore;
  int am = tid >> 1;
  int arow = m0 + am; if (arow >= mrows) arow = mrows - 1;
  const float* Arow = A + (size_t)arow * K;
  int amt = am >> 4;
  int bk = tid >> 3;
  int bnb = (tid & 7) * 4;
  int bg = bk >> 3, bslot = bk & 7;
  f32x4 acc[4][4];
#pragma unroll
  for (int i = 0; i < 4; ++i)
#pragma unroll
    for (int j = 0; j < 4; ++j) acc[i][j] = (f32x4){0.f, 0.f, 0.f, 0.f};
  for (int kb = k0; kb < k1; kb += 32) {
    __syncthreads();
#pragma unroll
    for (int i = 0; i < 4; ++i) {
      int kq = (tid & 1) * 4 + i * 8;
      float4 a = *(const float4*)(Arow + kb + kq);
      unsigned short h0, h1, h2, h3, l0, l1, l2, l3;
      split2(a.x, h0, l0); split2(a.y, h1, l1);
      split2(a.z, h2, l2); split2(a.w, h3, l3);
      int lane_t = (am & 15) + 16 * (kq >> 3);
      int sb = kq & 4;
      *(us4*)&sA[0][amt][lane_t][sb] = (us4){h0, h1, h2, h3};
      *(us4*)&sA[1][amt][lane_t][sb] = (us4){l0, l1, l2, l3};
    }
    {
      const float* Brow = Bm + (size_t)(kb + bk) * N + n0g;
#pragma unroll
      for (int i = 0; i < 4; ++i) {
        int n = bnb + i * 32;
        int nt = n >> 4, nr = n & 15;
        float4 b = *(const float4*)(Brow + n);
        float be[4] = {b.x, b.y, b.z, b.w};
#pragma unroll
        for (int e = 0; e < 4; ++e) {
          unsigned short hh, ll;
          split2(be[e], hh, ll);
          sB[0][nt][nr + e + 16 * bg][bslot] = hh;
          sB[1][nt][nr + e + 16 * bg][bslot] = ll;
        }
      }
    }
    __syncthreads();
    if (!activeM) continue;
    bf16x8 ah[4], al[4], bh[4], bl[4];
#pragma unroll
    for (int t = 0; t < 4; ++t) {
      ah[t] = *(const bf16x8*)&sA[0][wr * 4 + t][l][0];
      al[t] = *(const bf16x8*)&sA[1][wr * 4 + t][l][0];
      bh[t] = *(const bf16x8*)&sB[0][wc * 4 + t][l][0];
      bl[t] = *(const bf16x8*)&sB[1][wc * 4 + t][l][0];
    }
#pragma unroll
    for (int mt = 0; mt < 4; ++mt)
#pragma unroll
      for (int nt = 0; nt < 4; ++nt) {
        acc[mt][nt] = __builtin_amdgcn_mfma_f32_16x16x32_bf16(ah[mt], bh[nt], acc[mt][nt], 0, 0, 0);
        acc[mt][nt] = __builtin_amdgcn_mfma_f32_16x16x32_bf16(ah[mt], bl[nt], acc[mt][nt], 0, 0, 0);
        acc[mt][nt] = __builtin_amdgcn_mfma_f32_16x16x32_bf16(al[mt], bh[nt], acc[mt][nt], 0, 0, 0);
      }
  }
  if (!activeM) return;
  float* Cz = C + (size_t)z * mstore * N;
#pragma unroll
  for (int mt = 0; mt < 4; ++mt)
#pragma unroll
    for (int nt = 0; nt < 4; ++nt) {
      int col = n0g + wc * 64 + nt * 16 + (l & 15);
      float badd = bias ? bias[col] : 0.f;
#pragma unroll
      for (int r = 0; r < 4; ++r) {
        int row = m0 + wr * 64 + mt * 16 + ((l >> 4) << 2) + r;
        if (row < mstore) Cz[(size_t)row * N + col] = acc[mt][nt][r] + badd;
      }
    }
}

__global__ __launch_bounds__(64) void k_adj_fb(const float* __restrict__ G,
                                               const float* __restrict__ S,
                                               float* __restrict__ tok) {
  __shared__ float Fm[64][64];
  __shared__ float nrm[64], mm[64];
  int b = blockIdx.x >> 2, lz = blockIdx.x & 3;
  int j = threadIdx.x;
  const float* Gb = G + ((size_t)lz * B16 + b) * 4096;
  const float* Sb = S + ((size_t)lz * B16 + b) * 64;
  float nj = sqrtf(Gb[j * 64 + j]);
  nrm[j] = nj;
  mm[j] = Sb[j] / nj;
  __syncthreads();
  for (int i = 0; i < 64; ++i) {
    float g = Gb[i * 64 + j];
    float sim = g / (nrm[i] * nj);
    float F = mm[i] * mm[j] * sim * sim;
    float v = F;
    bool act = true;
    float kth = 0.f;
#pragma unroll
    for (int it = 0; it < 8; ++it) {
      float mv = wmax64(act ? v : -INFINITY);
      kth = mv;
      unsigned long long ball = __ballot(act && (v == mv));
      int first = __ffsll(ball) - 1;
      if (j == first) act = false;
    }
    float fm = (F >= kth) ? F : 0.f;
    Fm[i][j] = fmaxf(fm, 0.f);
  }
  __syncthreads();
  float* tb = tok + ((size_t)b * 4 + lz) * 4096;
  for (int i = 0; i < 64; ++i) tb[i * 64 + j] = 0.5f * (Fm[i][j] + Fm[j][i]);
}

__global__ __launch_bounds__(256) void k_qkv_reduce(const float* __restrict__ Cp,
                                                    const float* __restrict__ bq,
                                                    const float* __restrict__ bk,
                                                    const float* __restrict__ bv,
                                                    float* __restrict__ q,
                                                    float* __restrict__ k,
                                                    float* __restrict__ v) {
  int idx = blockIdx.x * 256 + threadIdx.x;
  int mat = idx >> 18;
  int rn = idx & ((1 << 18) - 1);
  int n = rn & 4095;
  const float* base = Cp + (size_t)mat * 4 * 262144;
  float s = base[rn] + base[rn + 262144] + base[rn + 2 * 262144] + base[rn + 3 * 262144];
  if (mat == 0) q[rn] = s + bq[n];
  else if (mat == 1) k[rn] = s + bk[n];
  else v[rn] = s + bv[n];
}

__global__ __launch_bounds__(64) void k_attn_fb(const float* __restrict__ q,
                                                const float* __restrict__ k,
                                                const float* __restrict__ v,
                                                float* __restrict__ ctx) {
  int hd = blockIdx.x, b = blockIdx.y;
  int t = threadIdx.x;
  float qr[4][4], kr[4][4], vr[4][4];
#pragma unroll
  for (int l = 0; l < 4; ++l)
#pragma unroll
    for (int s = 0; s < 4; ++s) {
      size_t off = ((size_t)(b * 4 + l)) * 4096 + hd * 256 + t + s * 64;
      qr[l][s] = q[off]; kr[l][s] = k[off]; vr[l][s] = v[off];
    }
  float sc[4][4];
#pragma unroll
  for (int l = 0; l < 4; ++l)
#pragma unroll
    for (int m = 0; m < 4; ++m) {
      float p = 0.f;
#pragma unroll
      for (int s = 0; s < 4; ++s) p = fmaf(qr[l][s], kr[m][s], p);
#pragma unroll
      for (int off = 32; off; off >>= 1) p += __shfl_xor(p, off);
      sc[l][m] = p * (1.0f / 16.0f);
    }
  float at[4][4];
#pragma unroll
  for (int l = 0; l < 4; ++l) {
    float mx = fmaxf(fmaxf(sc[l][0], sc[l][1]), fmaxf(sc[l][2], sc[l][3]));
    float e0 = expf(sc[l][0] - mx), e1 = expf(sc[l][1] - mx);
    float e2 = expf(sc[l][2] - mx), e3 = expf(sc[l][3] - mx);
    float d = e0 + e1 + e2 + e3;
    at[l][0] = e0 / d; at[l][1] = e1 / d; at[l][2] = e2 / d; at[l][3] = e3 / d;
  }
#pragma unroll
  for (int l = 0; l < 4; ++l)
#pragma unroll
    for (int s = 0; s < 4; ++s) {
      float c = 0.f;
#pragma unroll
      for (int m = 0; m < 4; ++m) c = fmaf(at[l][m], vr[m][s], c);
      ctx[((size_t)(b * 4 + l)) * 4096 + hd * 256 + t + s * 64] = c;
    }
}

__global__ __launch_bounds__(256) void k_out_reduce(const float* __restrict__ Cp,
                                                    const float* __restrict__ bo,
                                                    float* __restrict__ out) {
  int idx = blockIdx.x * 256 + threadIdx.x;
  int n = idx & 4095;
  float s = bo[n];
#pragma unroll
  for (int p = 0; p < 8; ++p) s += Cp[(size_t)p * 262144 + idx];
  out[idx] = (s > 0.5f) ? s : 0.f;
}

// ================= launch =================
extern "C" void kernel_launch(void* const* d_in, const int* in_sizes, int n_in,
                              void* d_out, int out_size, void* d_ws, size_t ws_size,
                              hipStream_t stream) {
  const float* x     = (const float*)d_in[0];
  const float* W_mlp = (const float*)d_in[1];
  const float* b_mlp = (const float*)d_in[2];
  const float* Wq = (const float*)d_in[3]; const float* bq = (const float*)d_in[4];
  const float* Wk = (const float*)d_in[5]; const float* bk = (const float*)d_in[6];
  const float* Wv = (const float*)d_in[7]; const float* bv = (const float*)d_in[8];
  const float* Wo = (const float*)d_in[9]; const float* bo = (const float*)d_in[10];
  float* out = (float*)d_out;
  float* ws = (float*)d_ws;

  float* h   = ws;                       // 4,194,304 floats (fallback only)
  float* Gp  = ws + 8388608;             // 32 x 65536 = 2,097,152
  float* Sp  = ws + 10485760;            // 32,768
  float* G   = ws + 10518528;
  float* S   = ws + 10780672;

  const size_t NEED = 50368512ull * 4ull;   // ~202 MB
  if (ws_size >= NEED) {
    // ---------- fast path ----------
    float* q   = ws + 10784768;
    float* kk  = ws + 11046912;
    float* vv  = ws + 11309056;
    unsigned short* AhT = (unsigned short*)(ws + 11571200);   // 4,194,304 shorts
    unsigned short* AlT = (unsigned short*)(ws + 13668352);
    unsigned short* WhT = (unsigned short*)(ws + 15765504);   // 16,777,216 shorts
    unsigned short* WlT = (unsigned short*)(ws + 24154112);
    float* Cp           = ws + 32542720;                      // 16,777,216 floats
    unsigned short* tokh = (unsigned short*)(ws + 49319936);
    unsigned short* tokl = (unsigned short*)(ws + 49582080);
    unsigned short* ctxh = (unsigned short*)(ws + 49844224);
    unsigned short* ctxl = (unsigned short*)(ws + 50106368);  // end 50,368,512 floats

    k_transpose<<<dim3(64, 16), 256, 0, stream>>>(x, h, AhT, AlT, 2);

    // gram slot 0 from AhT/AlT (bs1=2048, ks_stride=4096)
    k_gram_mfma<<<dim3(8, 16), 256, 0, stream>>>(AhT, AlT, Gp, Sp, 2048, 4096, 16);
    k_gred<<<260, 256, 0, stream>>>(Gp, Sp, G, S, 0, 8);

    for (int l = 0; l < 3; ++l) {
      k_wsplit<<<dim3(32, 128), 256, 0, stream>>>(W_mlp + (size_t)l * 16777216, WhT, WlT);
      k_gemm_bf16<<<dim3(32, 8, 2), 512, 0, stream>>>(AhT, AlT, WhT, WlT, Cp,
                                                      128, 2, 4096, 1024);
      k_gram_fuse<<<dim3(32, 16), 256, 0, stream>>>(Cp, b_mlp + (size_t)l * 4096,
                                                    Gp, Sp, 2);
      k_gred<<<260, 256, 0, stream>>>(Gp, Sp, G, S, l + 1, 32);
    }

    k_adj_t<<<64, 256, 0, stream>>>(G, S, tokh, tokl);

    // QKV: one launch, 3 mats x 16 K-splits, W split on-the-fly
    k_gemm_wsf32<<<dim3(32, 1, 48), 512, 0, stream>>>(tokh, tokl, Wq, Wk, Wv, Cp, 16);
    k_redqkv<<<3072, 256, 0, stream>>>(Cp, bq, bk, bv, q, kk, vv);

    k_attn_t<<<dim3(16, 16), 64, 0, stream>>>(q, kk, vv, ctxh, ctxl);

    k_gemm_wsf32<<<dim3(32, 1, 16), 512, 0, stream>>>(ctxh, ctxl, Wo, Wo, Wo, Cp, 16);
    k_redN<<<1024, 256, 0, stream>>>(Cp, bo, out, 16, 1);
  } else {
    // ---------- fallback: round-3 proven path ----------
    float* hv  = ws + 4194304;
    float* tok = ws + 10784768;
    float* q   = ws + 11046912;
    float* kk  = ws + 11309056;
    float* vv  = ws + 11571200;
    float* ctx = ws + 11833344;
    float* qkvp = hv;
    float* op   = h;

    k_transpose<<<dim3(64, 16), 256, 0, stream>>>(x, h, (unsigned short*)0,
                                                  (unsigned short*)0, 0);
    k_gram_partial<<<dim3(NCHUNK, 16), 256, 0, stream>>>(h, Gp, Sp);
    k_gram_reduce<<<260, 256, 0, stream>>>(Gp, Sp, G, S, 0);
    for (int l = 0; l < 3; ++l) {
      const float* Wl = W_mlp + (size_t)l * PDIM * 4096;
      const float* bl = b_mlp + (size_t)l * 4096;
      k_gemm_mfma<<<dim3(32, 8, 1), 256, 0, stream>>>(h, Wl, Wl, Wl, bl, hv,
                                                      1024, 1024, 4096, 4096, 1);
      k_gram_partial<<<dim3(NCHUNK, 16), 256, 0, stream>>>(hv, Gp, Sp);
      k_gram_reduce<<<260, 256, 0, stream>>>(Gp, Sp, G, S, l + 1);
    }
    k_adj_fb<<<64, 64, 0, stream>>>(G, S, tok);
    k_gemm_mfma<<<dim3(32, 1, 12), 256, 0, stream>>>(tok, Wq, Wk, Wv, nullptr, qkvp,
                                                     64, 64, 4096, 4096, 4);
    k_qkv_reduce<<<3072, 256, 0, stream>>>(qkvp, bq, bk, bv, q, kk, vv);
    k_attn_fb<<<dim3(16, 16), 64, 0, stream>>>(q, kk, vv, ctx);
    k_gemm_mfma<<<dim3(32, 1, 8), 256, 0, stream>>>(ctx, Wo, Wo, Wo, nullptr, op,
                                                    64, 64, 4096, 4096, 8);
    k_out_reduce<<<1024, 256, 0, stream>>>(op, bo, out);
  }
}